// Round 1
// baseline (412.795 us; speedup 1.0000x reference)
//
#include <hip/hip_runtime.h>
#include <math.h>

// Problem constants
#define NIMG 512          // B*C = 64*8
#define HH   256          // H
#define MM   32           // M (kept modes per axis)
#define EPSF 1e-8f

// d_out float offsets (outputs concatenated flat in reference return order)
#define O0 0u             // modal_energies        [512][32][32]
#define O1 524288u        // modal_uncertainties   [512][32][32]
#define O2 1048576u       // energy_fractions      [512][32][32]
#define O3 1572864u       // weighted_importance   [512][32][32]
#define O4 2097152u       // uncertainty_spectrum  [32][32]
#define O5 2098176u       // energy_spectrum       [32][32]
#define O6 2099200u       // modal_errors          [512][32][32]
#define O7 2623488u       // calibration_scores    [32][32]

// d_ws float offsets
#define TW_OFF  0                            // 256 x (cos,sin) = 512 floats
#define PM_OFF  512                          // pred modes [512][32][32][2]
#define GM_OFF  (512 + NIMG*MM*MM*2)         // gt modes
#define TOT_OFF (512 + 2*NIMG*MM*MM*2)       // per-image total energy [512]

// ---------------------------------------------------------------------------
// Twiddle table: tw[t] = (cos(2*pi*t/256), sin(2*pi*t/256))
__global__ void init_tw_kernel(float* __restrict__ tw) {
  int t = threadIdx.x;  // 256 threads
  double th = (2.0 * M_PI / 256.0) * (double)t;
  tw[2*t]   = (float)cos(th);
  tw[2*t+1] = (float)sin(th);
}

// ---------------------------------------------------------------------------
// Truncated 2D DFT: one block per (image, tensor). 256 threads.
// Stage 1: T2[k1][n2] = sum_n1 x[n1][n2] * e^{-2pi i k1 n1/256}, k1 in [0,32)
//          thread t = n2 column; radix-2 fold over n1 (n1 vs n1+128).
// Stage 2: modes[k1][k2] = sum_n2 T2[k1][n2] * e^{-2pi i k2 n2/256}
//          thread t -> k1 = t>>3, k2 = (t&7) + 8q, q=0..3.
__global__ __launch_bounds__(256) void dft_kernel(
    const float* __restrict__ pred, const float* __restrict__ gt,
    const float* __restrict__ tw,
    float* __restrict__ Pm, float* __restrict__ Gm,
    float* __restrict__ tot, float* __restrict__ out_energy)
{
  // T2 stored [n2][k1] (float2), column add-rotate swizzle for conflict-free
  // stage-2 reads: logical col L of row r lives at phys ((L + 2*(r&15)) & 31).
  __shared__ float2 T2[256][32];   // 64 KiB

  const int t    = threadIdx.x;
  const int img  = blockIdx.x & (NIMG - 1);
  const int isGt = blockIdx.x >> 9;
  const float* __restrict__ x = (isGt ? gt : pred) + (size_t)img * (HH * HH);
  const float2* __restrict__ tw2 = (const float2*)tw;

  // ---- stage 1 ----
  float Er[16], Ei[16], Or[16], Oi[16];
#pragma unroll
  for (int j = 0; j < 16; ++j) { Er[j] = 0.f; Ei[j] = 0.f; Or[j] = 0.f; Oi[j] = 0.f; }

  for (int n1 = 0; n1 < 128; ++n1) {
    float a = x[n1 * HH + t];
    float b = x[(n1 + 128) * HH + t];
    float s = a + b;   // feeds even k1
    float d = a - b;   // feeds odd  k1
#pragma unroll
    for (int j = 0; j < 16; ++j) {
      int ie = (2 * j * n1) & 255;        // uniform -> scalar loads
      int io = (ie + n1) & 255;
      float2 e = tw2[ie];
      float2 o = tw2[io];
      Er[j] = fmaf(s,  e.x, Er[j]);
      Ei[j] = fmaf(-s, e.y, Ei[j]);
      Or[j] = fmaf(d,  o.x, Or[j]);
      Oi[j] = fmaf(-d, o.y, Oi[j]);
    }
  }

  const int sw = (t & 15) << 1;
#pragma unroll
  for (int j = 0; j < 16; ++j) {
    int c = (2 * j + sw) & 31;           // even -> float4 fits within row slot
    *(float4*)&T2[t][c] = make_float4(Er[j], Ei[j], Or[j], Oi[j]);
  }
  __syncthreads();

  // ---- stage 2 ----
  const int k1  = t >> 3;
  const int k2b = t & 7;
  float mr[4] = {0.f, 0.f, 0.f, 0.f}, mi[4] = {0.f, 0.f, 0.f, 0.f};
  for (int n2 = 0; n2 < 256; ++n2) {
    int phys = (k1 + ((n2 & 15) << 1)) & 31;
    float2 v = T2[n2][phys];
#pragma unroll
    for (int q = 0; q < 4; ++q) {
      int idx = ((k2b + 8 * q) * n2) & 255;   // per-lane (8 distinct) -> L1 hits
      float2 cs = tw2[idx];
      // (vr + i vi) * (cos - i sin)
      mr[q] = fmaf(v.x, cs.x, fmaf(v.y, cs.y, mr[q]));
      mi[q] = fmaf(v.y, cs.x, fmaf(-v.x, cs.y, mi[q]));
    }
  }
  __syncthreads();  // all T2 reads done; LDS reusable below

  float* __restrict__ Mo = (isGt ? Gm : Pm) + (size_t)img * (MM * MM * 2);
  float eacc = 0.f;
#pragma unroll
  for (int q = 0; q < 4; ++q) {
    int k2   = k2b + 8 * q;
    int midx = k1 * MM + k2;
    Mo[2 * midx]     = mr[q];
    Mo[2 * midx + 1] = mi[q];
    if (!isGt) {
      float en = fmaf(mr[q], mr[q], mi[q] * mi[q]);
      out_energy[(size_t)img * (MM * MM) + midx] = en;
      eacc += en;
    }
  }
  if (!isGt) {   // uniform per block
#pragma unroll
    for (int off = 32; off >= 1; off >>= 1) eacc += __shfl_down(eacc, off);
    float* wsf = (float*)&T2[0][0];
    if ((t & 63) == 0) wsf[t >> 6] = eacc;
    __syncthreads();
    if (t == 0) tot[img] = (wsf[0] + wsf[1]) + (wsf[2] + wsf[3]);
  }
}

// ---------------------------------------------------------------------------
// Per-mode MLP + elementwise outputs. One thread per (img, mode).
__global__ __launch_bounds__(256) void mlp_kernel(
    const float* __restrict__ Pm, const float* __restrict__ Gm,
    const float* __restrict__ tot,
    const float* __restrict__ W1, const float* __restrict__ b1,
    const float* __restrict__ W2, const float* __restrict__ b2,
    const float* __restrict__ W3, const float* __restrict__ b3,
    float* __restrict__ out)
{
  int gid = blockIdx.x * 256 + threadIdx.x;   // 0 .. 524287
  int img = gid >> 10;

  float2 pm = *(const float2*)&Pm[2 * (size_t)gid];
  float2 gm = *(const float2*)&Gm[2 * (size_t)gid];

  float er = pm.x - gm.x, ei = pm.y - gm.y;
  float merr   = fmaf(er, er, ei * ei);
  float energy = fmaf(pm.x, pm.x, pm.y * pm.y);
  float frac   = energy / (tot[img] + EPSF);

  // MLP: Linear(2,64)+ReLU -> Linear(64,32)+ReLU -> Linear(32,1) -> softplus
  float h1[64];
#pragma unroll
  for (int j = 0; j < 64; ++j)
    h1[j] = fmaxf(fmaf(pm.x, W1[j], fmaf(pm.y, W1[64 + j], b1[j])), 0.f);

  float h2[32];
#pragma unroll
  for (int k = 0; k < 32; ++k) h2[k] = b2[k];
#pragma unroll
  for (int j = 0; j < 64; ++j) {
#pragma unroll
    for (int k = 0; k < 32; ++k)
      h2[k] = fmaf(h1[j], W2[j * 32 + k], h2[k]);
  }
  float z = b3[0];
#pragma unroll
  for (int k = 0; k < 32; ++k) z = fmaf(fmaxf(h2[k], 0.f), W3[k], z);

  // softplus(z) = max(z,0) + log1p(exp(-|z|))
  float u = fmaxf(z, 0.f) + log1pf(expf(-fabsf(z)));

  out[O0 + gid] = energy;
  out[O1 + gid] = u;
  out[O2 + gid] = frac;
  out[O3 + gid] = frac * u;
  out[O6 + gid] = merr;
}

// ---------------------------------------------------------------------------
// Per-mode reductions over the 512-image axis: spectra + Pearson correlation.
// One block (1 wave) per mode.
__global__ __launch_bounds__(64) void corr_kernel(float* __restrict__ out)
{
  int mode = blockIdx.x;     // 0..1023
  int lane = threadIdx.x;    // 0..63

  double su = 0.0, se = 0.0, sen = 0.0, suu = 0.0, see = 0.0, sue = 0.0;
  for (int i = lane; i < NIMG; i += 64) {
    float u  = out[O1 + (size_t)i * 1024 + mode];
    float e  = out[O6 + (size_t)i * 1024 + mode];
    float en = out[O0 + (size_t)i * 1024 + mode];
    su  += (double)u;  se  += (double)e;  sen += (double)en;
    suu += (double)u * (double)u;
    see += (double)e * (double)e;
    sue += (double)u * (double)e;
  }
#pragma unroll
  for (int off = 32; off >= 1; off >>= 1) {
    su  += __shfl_down(su,  off);
    se  += __shfl_down(se,  off);
    sen += __shfl_down(sen, off);
    suu += __shfl_down(suu, off);
    see += __shfl_down(see, off);
    sue += __shfl_down(sue, off);
  }
  if (lane == 0) {
    const double N = (double)NIMG;
    double num = sue - su * se / N;
    double du  = suu - su * su / N;
    double de  = see - se * se / N;
    double den = sqrt(du * de);
    out[O4 + mode] = (float)(su / N);
    out[O5 + mode] = (float)(sen / N);
    out[O7 + mode] = (float)(num / (den + 1e-8));
  }
}

// ---------------------------------------------------------------------------
extern "C" void kernel_launch(void* const* d_in, const int* in_sizes, int n_in,
                              void* d_out, int out_size, void* d_ws, size_t ws_size,
                              hipStream_t stream)
{
  const float* pred = (const float*)d_in[0];
  // d_in[1] (uncertainty) is unused by the reference
  const float* gt   = (const float*)d_in[2];
  const float* W1   = (const float*)d_in[3];
  const float* b1   = (const float*)d_in[4];
  const float* W2   = (const float*)d_in[5];
  const float* b2   = (const float*)d_in[6];
  const float* W3   = (const float*)d_in[7];
  const float* b3   = (const float*)d_in[8];

  float* out = (float*)d_out;
  float* ws  = (float*)d_ws;
  float* tw  = ws + TW_OFF;
  float* Pm  = ws + PM_OFF;
  float* Gm  = ws + GM_OFF;
  float* tot = ws + TOT_OFF;

  hipLaunchKernelGGL(init_tw_kernel, dim3(1), dim3(256), 0, stream, tw);
  hipLaunchKernelGGL(dft_kernel, dim3(1024), dim3(256), 0, stream,
                     pred, gt, tw, Pm, Gm, tot, out + O0);
  hipLaunchKernelGGL(mlp_kernel, dim3(2048), dim3(256), 0, stream,
                     Pm, Gm, tot, W1, b1, W2, b2, W3, b3, out);
  hipLaunchKernelGGL(corr_kernel, dim3(1024), dim3(64), 0, stream, out);
}

// Round 2
// 199.472 us; speedup vs baseline: 2.0694x; 2.0694x over previous
//
#include <hip/hip_runtime.h>
#include <math.h>

// Problem constants
#define NIMG 512          // B*C = 64*8
#define HH   256          // H
#define MM   32           // M (kept modes per axis)
#define EPSF 1e-8f
#define PAD  17           // padded k1-stride (float2 units) for T2

// d_out float offsets (outputs concatenated flat in reference return order)
#define O0 0u             // modal_energies        [512][32][32]
#define O1 524288u        // modal_uncertainties   [512][32][32]
#define O2 1048576u       // energy_fractions      [512][32][32]
#define O3 1572864u       // weighted_importance   [512][32][32]
#define O4 2097152u       // uncertainty_spectrum  [32][32]
#define O5 2098176u       // energy_spectrum       [32][32]
#define O6 2099200u       // modal_errors          [512][32][32]
#define O7 2623488u       // calibration_scores    [32][32]

// d_ws float offsets
#define TW_OFF  0                            // 256 x (cos,sin) = 512 floats
#define PM_OFF  512                          // pred modes [512][32][32][2]
#define GM_OFF  (512 + NIMG*MM*MM*2)         // gt modes
#define TOT_OFF (512 + 2*NIMG*MM*MM*2)       // per-image total energy [512]

// ---------------------------------------------------------------------------
// Twiddle table: tw[t] = (cos(2*pi*t/256), sin(2*pi*t/256))
__global__ void init_tw_kernel(float* __restrict__ tw) {
  int t = threadIdx.x;  // 256 threads
  double th = (2.0 * M_PI / 256.0) * (double)t;
  tw[2*t]   = (float)cos(th);
  tw[2*t+1] = (float)sin(th);
}

// ---------------------------------------------------------------------------
// Truncated 2D DFT: one block per (image, tensor). 256 threads.
// Stage 1 (radix-4 over n1): thread t = column n2; 64 folds of 4 rows each;
//   accumulates all 32 k1 outputs in registers (64 floats).
// Stage 2 (two passes over k1-halves via 36KB LDS): thread -> (k1l, k2b);
//   two twiddle recurrence chains (k2b, k2b+16), 16 FMA per n2 step.
__global__ __launch_bounds__(256, 4) void dft_kernel(
    const float* __restrict__ pred, const float* __restrict__ gt,
    const float* __restrict__ tw,
    float* __restrict__ Pm, float* __restrict__ Gm,
    float* __restrict__ tot, float* __restrict__ out_energy)
{
  __shared__ float2 T2[256 * PAD];   // 34816 B: [n2][k1 0..15], pad 17
  __shared__ float2 tws[256];        // 2 KB twiddle table
  __shared__ float  red[4];          // block energy reduction

  const int t    = threadIdx.x;
  const int img  = blockIdx.x & (NIMG - 1);
  const int isGt = blockIdx.x >> 9;
  const float* __restrict__ x = (isGt ? gt : pred) + (size_t)img * (HH * HH);

  tws[t] = ((const float2*)tw)[t];
  __syncthreads();

  // ---- stage 1: radix-4 over rows ----
  float accR[32], accI[32];
#pragma unroll
  for (int k = 0; k < 32; ++k) { accR[k] = 0.f; accI[k] = 0.f; }

  for (int n1 = 0; n1 < 64; ++n1) {
    float a = x[ n1        * HH + t];
    float b = x[(n1 +  64) * HH + t];
    float c = x[(n1 + 128) * HH + t];
    float d = x[(n1 + 192) * HH + t];
    float s0 = a + c, s1 = a - c, s2 = b + d, s3 = b - d;
    float e0 = s0 + s2, e2 = s0 - s2;
    const int step = (n1 << 2) & 255;

    // r = 0 (real term e0)
    int idx = 0;
#pragma unroll
    for (int m = 0; m < 8; ++m) {
      float2 w = tws[idx]; idx = (idx + step) & 255;
      accR[4*m]   = fmaf( e0, w.x, accR[4*m]);
      accI[4*m]   = fmaf(-e0, w.y, accI[4*m]);
    }
    // r = 2 (real term e2)
    idx = (n1 << 1) & 255;
#pragma unroll
    for (int m = 0; m < 8; ++m) {
      float2 w = tws[idx]; idx = (idx + step) & 255;
      accR[4*m+2] = fmaf( e2, w.x, accR[4*m+2]);
      accI[4*m+2] = fmaf(-e2, w.y, accI[4*m+2]);
    }
    // r = 1 (complex term (s1, -s3))
    idx = n1;
#pragma unroll
    for (int m = 0; m < 8; ++m) {
      float2 w = tws[idx]; idx = (idx + step) & 255;
      accR[4*m+1] = fmaf( s1, w.x, fmaf(-s3, w.y, accR[4*m+1]));
      accI[4*m+1] = fmaf(-s3, w.x, fmaf(-s1, w.y, accI[4*m+1]));
    }
    // r = 3 (complex term (s1, +s3))
    idx = (3 * n1) & 255;
#pragma unroll
    for (int m = 0; m < 8; ++m) {
      float2 w = tws[idx]; idx = (idx + step) & 255;
      accR[4*m+3] = fmaf( s1, w.x, fmaf( s3, w.y, accR[4*m+3]));
      accI[4*m+3] = fmaf( s3, w.x, fmaf(-s1, w.y, accI[4*m+3]));
    }
  }

  // ---- stage 2: two passes over k1-halves ----
  float* __restrict__ Mo = (isGt ? Gm : Pm) + (size_t)img * (MM * MM * 2);
  const int k1l = t >> 4;      // 0..15
  const int k2b = t & 15;      // 0..15
  // recurrence multipliers for k2 = k2b and k2b+16 (e^{-2*pi*i*k2/256})
  const float r0x = tws[k2b].x,      r0y = -tws[k2b].y;
  const float r1x = tws[k2b + 16].x, r1y = -tws[k2b + 16].y;
  float eacc = 0.f;

#pragma unroll
  for (int p = 0; p < 2; ++p) {
    __syncthreads();   // previous pass reads (or tws broadcast) complete
#pragma unroll
    for (int m = 4*p; m < 4*p + 4; ++m) {
#pragma unroll
      for (int r = 0; r < 4; ++r) {
        int k1 = 4*m + r;
        T2[t * PAD + (k1 & 15)] = make_float2(accR[k1], accI[k1]);
      }
    }
    __syncthreads();

    float w0r = 1.f, w0i = 0.f, w1r = 1.f, w1i = 0.f;
    float a0r = 0.f, a0i = 0.f, a1r = 0.f, a1i = 0.f;
    for (int n2 = 0; n2 < 256; ++n2) {
      float2 v = T2[n2 * PAD + k1l];
      a0r = fmaf(v.x, w0r, fmaf(-v.y, w0i, a0r));
      a0i = fmaf(v.x, w0i, fmaf( v.y, w0r, a0i));
      a1r = fmaf(v.x, w1r, fmaf(-v.y, w1i, a1r));
      a1i = fmaf(v.x, w1i, fmaf( v.y, w1r, a1i));
      float n0r = w0r * r0x - w0i * r0y;
      float n0i = w0r * r0y + w0i * r0x;
      float n1r = w1r * r1x - w1i * r1y;
      float n1i = w1r * r1y + w1i * r1x;
      w0r = n0r; w0i = n0i; w1r = n1r; w1i = n1i;
    }

    const int k1 = k1l + 16 * p;
#pragma unroll
    for (int j = 0; j < 2; ++j) {
      float mr = j ? a1r : a0r;
      float mi = j ? a1i : a0i;
      int   k2 = k2b + 16 * j;
      int midx = k1 * MM + k2;
      Mo[2 * midx]     = mr;
      Mo[2 * midx + 1] = mi;
      if (!isGt) {
        float en = fmaf(mr, mr, mi * mi);
        out_energy[(size_t)img * (MM * MM) + midx] = en;
        eacc += en;
      }
    }
  }

  if (!isGt) {   // block-uniform branch
#pragma unroll
    for (int off = 32; off >= 1; off >>= 1) eacc += __shfl_down(eacc, off);
    __syncthreads();
    if ((t & 63) == 0) red[t >> 6] = eacc;
    __syncthreads();
    if (t == 0) tot[img] = (red[0] + red[1]) + (red[2] + red[3]);
  }
}

// ---------------------------------------------------------------------------
// Per-mode MLP + elementwise outputs. One thread per (img, mode).
__global__ __launch_bounds__(256) void mlp_kernel(
    const float* __restrict__ Pm, const float* __restrict__ Gm,
    const float* __restrict__ tot,
    const float* __restrict__ W1, const float* __restrict__ b1,
    const float* __restrict__ W2, const float* __restrict__ b2,
    const float* __restrict__ W3, const float* __restrict__ b3,
    float* __restrict__ out)
{
  int gid = blockIdx.x * 256 + threadIdx.x;   // 0 .. 524287
  int img = gid >> 10;

  float2 pm = *(const float2*)&Pm[2 * (size_t)gid];
  float2 gm = *(const float2*)&Gm[2 * (size_t)gid];

  float er = pm.x - gm.x, ei = pm.y - gm.y;
  float merr   = fmaf(er, er, ei * ei);
  float energy = fmaf(pm.x, pm.x, pm.y * pm.y);
  float frac   = energy / (tot[img] + EPSF);

  float h1[64];
#pragma unroll
  for (int j = 0; j < 64; ++j)
    h1[j] = fmaxf(fmaf(pm.x, W1[j], fmaf(pm.y, W1[64 + j], b1[j])), 0.f);

  float h2[32];
#pragma unroll
  for (int k = 0; k < 32; ++k) h2[k] = b2[k];
#pragma unroll
  for (int j = 0; j < 64; ++j) {
#pragma unroll
    for (int k = 0; k < 32; ++k)
      h2[k] = fmaf(h1[j], W2[j * 32 + k], h2[k]);
  }
  float z = b3[0];
#pragma unroll
  for (int k = 0; k < 32; ++k) z = fmaf(fmaxf(h2[k], 0.f), W3[k], z);

  float u = fmaxf(z, 0.f) + log1pf(expf(-fabsf(z)));

  out[O0 + gid] = energy;
  out[O1 + gid] = u;
  out[O2 + gid] = frac;
  out[O3 + gid] = frac * u;
  out[O6 + gid] = merr;
}

// ---------------------------------------------------------------------------
// Per-mode reductions over the 512-image axis: spectra + Pearson correlation.
__global__ __launch_bounds__(64) void corr_kernel(float* __restrict__ out)
{
  int mode = blockIdx.x;     // 0..1023
  int lane = threadIdx.x;    // 0..63

  double su = 0.0, se = 0.0, sen = 0.0, suu = 0.0, see = 0.0, sue = 0.0;
  for (int i = lane; i < NIMG; i += 64) {
    float u  = out[O1 + (size_t)i * 1024 + mode];
    float e  = out[O6 + (size_t)i * 1024 + mode];
    float en = out[O0 + (size_t)i * 1024 + mode];
    su  += (double)u;  se  += (double)e;  sen += (double)en;
    suu += (double)u * (double)u;
    see += (double)e * (double)e;
    sue += (double)u * (double)e;
  }
#pragma unroll
  for (int off = 32; off >= 1; off >>= 1) {
    su  += __shfl_down(su,  off);
    se  += __shfl_down(se,  off);
    sen += __shfl_down(sen, off);
    suu += __shfl_down(suu, off);
    see += __shfl_down(see, off);
    sue += __shfl_down(sue, off);
  }
  if (lane == 0) {
    const double N = (double)NIMG;
    double num = sue - su * se / N;
    double du  = suu - su * su / N;
    double de  = see - se * se / N;
    double den = sqrt(du * de);
    out[O4 + mode] = (float)(su / N);
    out[O5 + mode] = (float)(sen / N);
    out[O7 + mode] = (float)(num / (den + 1e-8));
  }
}

// ---------------------------------------------------------------------------
extern "C" void kernel_launch(void* const* d_in, const int* in_sizes, int n_in,
                              void* d_out, int out_size, void* d_ws, size_t ws_size,
                              hipStream_t stream)
{
  const float* pred = (const float*)d_in[0];
  const float* gt   = (const float*)d_in[2];
  const float* W1   = (const float*)d_in[3];
  const float* b1   = (const float*)d_in[4];
  const float* W2   = (const float*)d_in[5];
  const float* b2   = (const float*)d_in[6];
  const float* W3   = (const float*)d_in[7];
  const float* b3   = (const float*)d_in[8];

  float* out = (float*)d_out;
  float* ws  = (float*)d_ws;
  float* tw  = ws + TW_OFF;
  float* Pm  = ws + PM_OFF;
  float* Gm  = ws + GM_OFF;
  float* tot = ws + TOT_OFF;

  hipLaunchKernelGGL(init_tw_kernel, dim3(1), dim3(256), 0, stream, tw);
  hipLaunchKernelGGL(dft_kernel, dim3(1024), dim3(256), 0, stream,
                     pred, gt, tw, Pm, Gm, tot, out + O0);
  hipLaunchKernelGGL(mlp_kernel, dim3(2048), dim3(256), 0, stream,
                     Pm, Gm, tot, W1, b1, W2, b2, W3, b3, out);
  hipLaunchKernelGGL(corr_kernel, dim3(1024), dim3(64), 0, stream, out);
}

// Round 3
// 139.787 us; speedup vs baseline: 2.9530x; 1.4270x over previous
//
#include <hip/hip_runtime.h>
#include <math.h>

// Problem constants
#define NIMG 512          // B*C = 64*8
#define HH   256          // H
#define MM   32           // M (kept modes per axis)
#define EPSF 1e-8f
#define PAD  17           // padded k1-stride (float2 units) for T2

// d_out float offsets (outputs concatenated flat in reference return order)
#define O0 0u             // modal_energies        [512][32][32]
#define O1 524288u        // modal_uncertainties   [512][32][32]
#define O2 1048576u       // energy_fractions      [512][32][32]
#define O3 1572864u       // weighted_importance   [512][32][32]
#define O4 2097152u       // uncertainty_spectrum  [32][32]
#define O5 2098176u       // energy_spectrum       [32][32]
#define O6 2099200u       // modal_errors          [512][32][32]
#define O7 2623488u       // calibration_scores    [32][32]

// d_ws float offsets
#define TW_OFF  0                            // 256 x (cos,sin) = 512 floats
#define PM_OFF  512                          // pred modes [512][32][32][2]
#define GM_OFF  (512 + NIMG*MM*MM*2)         // gt modes
#define TOT_OFF (512 + 2*NIMG*MM*MM*2)       // per-image total energy [512]

// ---------------------------------------------------------------------------
// Twiddle table: tw[t] = (cos(2*pi*t/256), sin(2*pi*t/256))
__global__ void init_tw_kernel(float* __restrict__ tw) {
  int t = threadIdx.x;  // 256 threads
  double th = (2.0 * M_PI / 256.0) * (double)t;
  tw[2*t]   = (float)cos(th);
  tw[2*t+1] = (float)sin(th);
}

// ---------------------------------------------------------------------------
// Truncated 2D DFT: one block per (image, tensor). 256 threads.
// Stage 1 (DIT-8 over n1 = a + 32b): per a, constant-twiddle 8-pt real DFT
//   over b in registers, then X[8m+r] += W32^{a m} * (W256^{a r} * Z[r]).
//   All twiddle LDS reads are wave-uniform (broadcast), 10 per a-iter.
// Stage 2 (two passes over k1-halves): radix-4 fold over n2 (64 iters),
//   residue r = k2 mod 4 is WAVE-uniform (wave w handles k2 === w mod 4),
//   twiddle by complex recurrence (64 steps, drift ~1e-6).
__global__ __launch_bounds__(256, 4) void dft_kernel(
    const float* __restrict__ pred, const float* __restrict__ gt,
    const float* __restrict__ tw,
    float* __restrict__ Pm, float* __restrict__ Gm,
    float* __restrict__ tot, float* __restrict__ out_energy)
{
  __shared__ float2 T2[256 * PAD];   // 34816 B: [n2][k1 0..15], pad 17
  __shared__ float2 tws[256];        // 2 KB twiddle table
  __shared__ float  red[4];          // block energy reduction

  const int t    = threadIdx.x;
  const int img  = blockIdx.x & (NIMG - 1);
  const int isGt = blockIdx.x >> 9;
  const float* __restrict__ x =
      (isGt ? gt : pred) + (size_t)img * (HH * HH) + t;

  tws[t] = ((const float2*)tw)[t];
  __syncthreads();

  // ---- stage 1: DIT-8 ----
  float accR[32], accI[32];
#pragma unroll
  for (int k = 0; k < 32; ++k) { accR[k] = 0.f; accI[k] = 0.f; }

  float vn[8];
#pragma unroll
  for (int b = 0; b < 8; ++b) vn[b] = x[b * 8192];   // a = 0 prefetch

#pragma unroll 1
  for (int a = 0; a < 32; ++a) {
    float v0 = vn[0], v1 = vn[1], v2 = vn[2], v3 = vn[3],
          v4 = vn[4], v5 = vn[5], v6 = vn[6], v7 = vn[7];
    if (a < 31) {
#pragma unroll
      for (int b = 0; b < 8; ++b) vn[b] = x[(a + 1) * 256 + b * 8192];
    }

    // 8-point real DFT over b (W8 constants only)
    float w0 = v0 + v4, w1 = v1 + v5, w2 = v2 + v6, w3 = v3 + v7;
    float d0 = v0 - v4, d1 = v1 - v5, d2 = v2 - v6, d3 = v3 - v7;
    float A0 = w0 + w2, A1 = w0 - w2, A2 = w1 + w3, A3 = w1 - w3;
    float Z0 = A0 + A2, Z4 = A0 - A2;          // real
    float Z2r = A1, Z2i = -A3;
    const float SQ = 0.70710678118654752f;
    float pp = SQ * (d1 - d3), qq2 = SQ * (d1 + d3);
    float Z1r = d0 + pp, Z1i = -(d2 + qq2);
    float Z3r = d0 - pp, Z3i = d2 - qq2;

    // m-step twiddles W32^{a m} = (mr, -ms), m = 1..3  (uniform reads)
    float2 tm1 = tws[(8 * a) & 255];
    float2 tm2 = tws[(16 * a) & 255];
    float2 tm3 = tws[(24 * a) & 255];
    float m1r = tm1.x, m1s = tm1.y;
    float m2r = tm2.x, m2s = tm2.y;
    float m3r = tm3.x, m3s = tm3.y;

    // X[8m+r] += (mr,-ms) * Y :  Xr += mr*Yr + ms*Yi ; Xi += mr*Yi - ms*Yr
#define ACC4(r, Yr, Yi)                                                  \
    accR[(r)]    += (Yr);  accI[(r)]    += (Yi);                         \
    accR[8+(r)]  = fmaf(m1r,(Yr), fmaf( m1s,(Yi), accR[8+(r)]));         \
    accI[8+(r)]  = fmaf(m1r,(Yi), fmaf(-m1s,(Yr), accI[8+(r)]));         \
    accR[16+(r)] = fmaf(m2r,(Yr), fmaf( m2s,(Yi), accR[16+(r)]));        \
    accI[16+(r)] = fmaf(m2r,(Yi), fmaf(-m2s,(Yr), accI[16+(r)]));        \
    accR[24+(r)] = fmaf(m3r,(Yr), fmaf( m3s,(Yi), accR[24+(r)]));        \
    accI[24+(r)] = fmaf(m3r,(Yi), fmaf(-m3s,(Yr), accI[24+(r)]));

    // r = 0 : Y = Z0 (real); X[0] stays real
    {
      accR[0] += Z0;
      accR[8]  = fmaf(m1r, Z0, accR[8]);  accI[8]  = fmaf(-m1s, Z0, accI[8]);
      accR[16] = fmaf(m2r, Z0, accR[16]); accI[16] = fmaf(-m2s, Z0, accI[16]);
      accR[24] = fmaf(m3r, Z0, accR[24]); accI[24] = fmaf(-m3s, Z0, accI[24]);
    }
    // r = 4 : Y = W256^{4a} * Z4 (Z4 real)
    {
      float2 tt = tws[(4 * a) & 255];
      float Yr = tt.x * Z4, Yi = -tt.y * Z4;
      ACC4(4, Yr, Yi)
    }
    // complex residues: Y = (tt.x, -tt.y) * (Zr, Zi)
#define CPLX_R(r, Zr, Zi)                                                \
    {                                                                    \
      float2 tt = tws[((r) * a) & 255];                                  \
      float Yr = fmaf(tt.x, (Zr),  tt.y * (Zi));                         \
      float Yi = fmaf(tt.x, (Zi), -tt.y * (Zr));                         \
      ACC4(r, Yr, Yi)                                                    \
    }
    CPLX_R(1, Z1r,  Z1i)
    CPLX_R(2, Z2r,  Z2i)
    CPLX_R(3, Z3r,  Z3i)
    CPLX_R(5, Z3r, -Z3i)   // Z5 = conj(Z3)
    CPLX_R(6, Z2r, -Z2i)   // Z6 = conj(Z2)
    CPLX_R(7, Z1r, -Z1i)   // Z7 = conj(Z1)
#undef CPLX_R
#undef ACC4
  }

  // ---- stage 2: two passes over k1-halves, radix-4 fold over n2 ----
  float* __restrict__ Mo = (isGt ? Gm : Pm) + (size_t)img * (MM * MM * 2);
  const int wv  = t >> 6;        // wave id = residue r (wave-uniform)
  const int l   = t & 63;
  const int k1l = l >> 2;        // 0..15
  const int qq  = l & 3;
  const int k2A = 4 * qq + wv;
  const int k2B = k2A + 16;
  float2 tA = tws[k2A]; const float rAx = tA.x, rAy = -tA.y;
  float2 tB = tws[k2B]; const float rBx = tB.x, rBy = -tB.y;
  float eacc = 0.f;

#pragma unroll 1
  for (int p = 0; p < 2; ++p) {
    __syncthreads();             // prior T2 reads complete
#pragma unroll
    for (int k = 0; k < 16; ++k)
      T2[t * PAD + k] = make_float2(accR[16 * p + k], accI[16 * p + k]);
    __syncthreads();

    float wAr = 1.f, wAi = 0.f, wBr = 1.f, wBi = 0.f;
    float XAr = 0.f, XAi = 0.f, XBr = 0.f, XBi = 0.f;
    for (int n2 = 0; n2 < 64; ++n2) {
      float2 T0 = T2[(n2      ) * PAD + k1l];
      float2 T1 = T2[(n2 +  64) * PAD + k1l];
      float2 Tc = T2[(n2 + 128) * PAD + k1l];
      float2 T3 = T2[(n2 + 192) * PAD + k1l];
      float yr, yi;
      if (wv == 0) {              // wave-uniform branch
        yr = (T0.x + Tc.x) + (T1.x + T3.x);
        yi = (T0.y + Tc.y) + (T1.y + T3.y);
      } else if (wv == 2) {
        yr = (T0.x + Tc.x) - (T1.x + T3.x);
        yi = (T0.y + Tc.y) - (T1.y + T3.y);
      } else {
        float s1r = T0.x - Tc.x, s1i = T0.y - Tc.y;
        float s3r = T1.x - T3.x, s3i = T1.y - T3.y;
        if (wv == 1) { yr = s1r + s3i; yi = s1i - s3r; }
        else         { yr = s1r - s3i; yi = s1i + s3r; }
      }
      XAr = fmaf(wAr, yr, fmaf(-wAi, yi, XAr));
      XAi = fmaf(wAr, yi, fmaf( wAi, yr, XAi));
      XBr = fmaf(wBr, yr, fmaf(-wBi, yi, XBr));
      XBi = fmaf(wBr, yi, fmaf( wBi, yr, XBi));
      float nAr = fmaf(wAr, rAx, -wAi * rAy);
      float nAi = fmaf(wAr, rAy,  wAi * rAx);
      float nBr = fmaf(wBr, rBx, -wBi * rBy);
      float nBi = fmaf(wBr, rBy,  wBi * rBx);
      wAr = nAr; wAi = nAi; wBr = nBr; wBi = nBi;
    }

    const int k1 = k1l + 16 * p;
    const int mA = k1 * MM + k2A;
    const int mB = k1 * MM + k2B;
    ((float2*)Mo)[mA] = make_float2(XAr, XAi);
    ((float2*)Mo)[mB] = make_float2(XBr, XBi);
    if (!isGt) {
      float eA = fmaf(XAr, XAr, XAi * XAi);
      float eB = fmaf(XBr, XBr, XBi * XBi);
      out_energy[(size_t)img * (MM * MM) + mA] = eA;
      out_energy[(size_t)img * (MM * MM) + mB] = eB;
      eacc += eA + eB;
    }
  }

  if (!isGt) {   // block-uniform branch
#pragma unroll
    for (int off = 32; off >= 1; off >>= 1) eacc += __shfl_down(eacc, off);
    if ((t & 63) == 0) red[t >> 6] = eacc;
    __syncthreads();
    if (t == 0) tot[img] = (red[0] + red[1]) + (red[2] + red[3]);
  }
}

// ---------------------------------------------------------------------------
// Per-mode MLP + elementwise outputs. One thread per (img, mode).
__global__ __launch_bounds__(256) void mlp_kernel(
    const float* __restrict__ Pm, const float* __restrict__ Gm,
    const float* __restrict__ tot,
    const float* __restrict__ W1, const float* __restrict__ b1,
    const float* __restrict__ W2, const float* __restrict__ b2,
    const float* __restrict__ W3, const float* __restrict__ b3,
    float* __restrict__ out)
{
  int gid = blockIdx.x * 256 + threadIdx.x;   // 0 .. 524287
  int img = gid >> 10;

  float2 pm = *(const float2*)&Pm[2 * (size_t)gid];
  float2 gm = *(const float2*)&Gm[2 * (size_t)gid];

  float er = pm.x - gm.x, ei = pm.y - gm.y;
  float merr   = fmaf(er, er, ei * ei);
  float energy = fmaf(pm.x, pm.x, pm.y * pm.y);
  float frac   = energy / (tot[img] + EPSF);

  float h1[64];
#pragma unroll
  for (int j = 0; j < 64; ++j)
    h1[j] = fmaxf(fmaf(pm.x, W1[j], fmaf(pm.y, W1[64 + j], b1[j])), 0.f);

  float h2[32];
#pragma unroll
  for (int k = 0; k < 32; ++k) h2[k] = b2[k];
#pragma unroll
  for (int j = 0; j < 64; ++j) {
#pragma unroll
    for (int k = 0; k < 32; ++k)
      h2[k] = fmaf(h1[j], W2[j * 32 + k], h2[k]);
  }
  float z = b3[0];
#pragma unroll
  for (int k = 0; k < 32; ++k) z = fmaf(fmaxf(h2[k], 0.f), W3[k], z);

  float u = fmaxf(z, 0.f) + log1pf(expf(-fabsf(z)));

  out[O0 + gid] = energy;
  out[O1 + gid] = u;
  out[O2 + gid] = frac;
  out[O3 + gid] = frac * u;
  out[O6 + gid] = merr;
}

// ---------------------------------------------------------------------------
// Per-mode reductions over the 512-image axis: spectra + Pearson correlation.
__global__ __launch_bounds__(64) void corr_kernel(float* __restrict__ out)
{
  int mode = blockIdx.x;     // 0..1023
  int lane = threadIdx.x;    // 0..63

  double su = 0.0, se = 0.0, sen = 0.0, suu = 0.0, see = 0.0, sue = 0.0;
  for (int i = lane; i < NIMG; i += 64) {
    float u  = out[O1 + (size_t)i * 1024 + mode];
    float e  = out[O6 + (size_t)i * 1024 + mode];
    float en = out[O0 + (size_t)i * 1024 + mode];
    su  += (double)u;  se  += (double)e;  sen += (double)en;
    suu += (double)u * (double)u;
    see += (double)e * (double)e;
    sue += (double)u * (double)e;
  }
#pragma unroll
  for (int off = 32; off >= 1; off >>= 1) {
    su  += __shfl_down(su,  off);
    se  += __shfl_down(se,  off);
    sen += __shfl_down(sen, off);
    suu += __shfl_down(suu, off);
    see += __shfl_down(see, off);
    sue += __shfl_down(sue, off);
  }
  if (lane == 0) {
    const double N = (double)NIMG;
    double num = sue - su * se / N;
    double du  = suu - su * su / N;
    double de  = see - se * se / N;
    double den = sqrt(du * de);
    out[O4 + mode] = (float)(su / N);
    out[O5 + mode] = (float)(sen / N);
    out[O7 + mode] = (float)(num / (den + 1e-8));
  }
}

// ---------------------------------------------------------------------------
extern "C" void kernel_launch(void* const* d_in, const int* in_sizes, int n_in,
                              void* d_out, int out_size, void* d_ws, size_t ws_size,
                              hipStream_t stream)
{
  const float* pred = (const float*)d_in[0];
  const float* gt   = (const float*)d_in[2];
  const float* W1   = (const float*)d_in[3];
  const float* b1   = (const float*)d_in[4];
  const float* W2   = (const float*)d_in[5];
  const float* b2   = (const float*)d_in[6];
  const float* W3   = (const float*)d_in[7];
  const float* b3   = (const float*)d_in[8];

  float* out = (float*)d_out;
  float* ws  = (float*)d_ws;
  float* tw  = ws + TW_OFF;
  float* Pm  = ws + PM_OFF;
  float* Gm  = ws + GM_OFF;
  float* tot = ws + TOT_OFF;

  hipLaunchKernelGGL(init_tw_kernel, dim3(1), dim3(256), 0, stream, tw);
  hipLaunchKernelGGL(dft_kernel, dim3(1024), dim3(256), 0, stream,
                     pred, gt, tw, Pm, Gm, tot, out + O0);
  hipLaunchKernelGGL(mlp_kernel, dim3(2048), dim3(256), 0, stream,
                     Pm, Gm, tot, W1, b1, W2, b2, W3, b3, out);
  hipLaunchKernelGGL(corr_kernel, dim3(1024), dim3(64), 0, stream, out);
}